// Round 2
// baseline (307.385 us; speedup 1.0000x reference)
//
#include <hip/hip_runtime.h>
#include <hip/hip_bf16.h>

// DifferentiableXGB: logits = epilogue(x @ W1^T + b1)
//   split[b,n] = sum_d x[b,d]*W1[n,d] + b1[n]          (n = t*4+k, N=400)
//   S[b,t] = sum_k split[b,t,k]
//   logits[b,j] = sum_t fw[t]*S[b,t]*sum_k sigmoid(split[b,t,k])*fc_w[j,k] + fc_b[j]
//
// V2: barrier-free K-loop. MFMA fragments loaded directly global->register
// (A: fp32 x, cvt in regs; B: bf16 W1 from ws). No LDS staging, no K-loop
// syncthreads, 1-step software prefetch. LDS only for the tiny epilogue
// cross-wave combine.

typedef __bf16 bf16x8 __attribute__((ext_vector_type(8)));
typedef unsigned short u16x8 __attribute__((ext_vector_type(8)));
typedef float f32x4 __attribute__((ext_vector_type(4)));

#define B_ROWS 32768
#define D_DIM  1024
#define N_COLS 400      // T*K = 100*4
#define THREADS 320     // 5 waves; wave w owns N-tiles [w*5, w*5+5), 25 tiles total
#define NTPW 5
#define MT   4          // 4 M-tiles of 16 -> 64 rows/block

__device__ __forceinline__ unsigned short f2bf(float f) {
    unsigned int u = __float_as_uint(f);
    u += 0x7FFFu + ((u >> 16) & 1u);   // RTNE
    return (unsigned short)(u >> 16);
}

__device__ __forceinline__ bf16x8 cvt8(float4 a, float4 b) {
    u16x8 u;
    u[0] = f2bf(a.x); u[1] = f2bf(a.y); u[2] = f2bf(a.z); u[3] = f2bf(a.w);
    u[4] = f2bf(b.x); u[5] = f2bf(b.y); u[6] = f2bf(b.z); u[7] = f2bf(b.w);
    return __builtin_bit_cast(bf16x8, u);
}

__global__ void cvt_w1_kernel(const float* __restrict__ w1,
                              unsigned short* __restrict__ out) {
    int i = (blockIdx.x * 256 + threadIdx.x) * 4;
    const float4 v = *reinterpret_cast<const float4*>(w1 + i);
    ushort4 o;
    o.x = f2bf(v.x); o.y = f2bf(v.y); o.z = f2bf(v.z); o.w = f2bf(v.w);
    *reinterpret_cast<ushort4*>(out + i) = o;
}

template <bool WS_BF16>
__global__ __launch_bounds__(THREADS, 2) void xgb_fused_v2(
    const float* __restrict__ x,
    const void*  __restrict__ w1_any,   // bf16 (ws path) or fp32 (fallback)
    const float* __restrict__ b1,
    const float* __restrict__ fw,
    const float* __restrict__ fcw,      // [2,4]
    const float* __restrict__ fcb,      // [2]
    float* __restrict__ out)            // [B,2]
{
    __shared__ float Pbuf[64 * 5 * 2];  // 2560 B — only LDS in the kernel

    const int tid  = threadIdx.x;
    const int wave = tid >> 6;
    const int lane = tid & 63;
    const int quad = lane >> 4;
    const int l15  = lane & 15;
    const int row0 = blockIdx.x * 64;

    // Per-lane base pointers. A-frag lane layout: A[m = l15][k = quad*8 + j].
    // B-frag lane layout (B^T rows = W1 rows): B[k = quad*8 + j][n = l15].
    const float* xb = x + (size_t)(row0 + l15) * D_DIM + quad * 8;

    f32x4 acc[MT][NTPW] = {};

    if (WS_BF16) {
        const unsigned short* bb = (const unsigned short*)w1_any
                                 + (size_t)(wave * (NTPW * 16) + l15) * D_DIM + quad * 8;

        // prologue: load step 0 fragments
        float4 a0[MT], a1[MT];
        uint4  bv[NTPW];
        #pragma unroll
        for (int m = 0; m < MT; ++m) {
            a0[m] = *reinterpret_cast<const float4*>(xb + m * 16 * D_DIM);
            a1[m] = *reinterpret_cast<const float4*>(xb + m * 16 * D_DIM + 4);
        }
        #pragma unroll
        for (int n = 0; n < NTPW; ++n)
            bv[n] = *reinterpret_cast<const uint4*>(bb + n * 16 * D_DIM);

        #pragma unroll 2
        for (int step = 0; step < 32; ++step) {
            float4 na0[MT], na1[MT];
            uint4  nbv[NTPW];
            if (step < 31) {
                const int off = (step + 1) * 32;
                #pragma unroll
                for (int m = 0; m < MT; ++m) {
                    na0[m] = *reinterpret_cast<const float4*>(xb + m * 16 * D_DIM + off);
                    na1[m] = *reinterpret_cast<const float4*>(xb + m * 16 * D_DIM + off + 4);
                }
                #pragma unroll
                for (int n = 0; n < NTPW; ++n)
                    nbv[n] = *reinterpret_cast<const uint4*>(bb + n * 16 * D_DIM + off);
            }
            bf16x8 af[MT];
            #pragma unroll
            for (int m = 0; m < MT; ++m) af[m] = cvt8(a0[m], a1[m]);
            #pragma unroll
            for (int n = 0; n < NTPW; ++n) {
                const bf16x8 bfr = __builtin_bit_cast(bf16x8, bv[n]);
                #pragma unroll
                for (int m = 0; m < MT; ++m)
                    acc[m][n] = __builtin_amdgcn_mfma_f32_16x16x32_bf16(
                        af[m], bfr, acc[m][n], 0, 0, 0);
            }
            if (step < 31) {
                #pragma unroll
                for (int m = 0; m < MT; ++m) { a0[m] = na0[m]; a1[m] = na1[m]; }
                #pragma unroll
                for (int n = 0; n < NTPW; ++n) bv[n] = nbv[n];
            }
        }
    } else {
        // fallback: fp32 W1 direct (no ws). Simple non-prefetched loop.
        const float* bf32 = (const float*)w1_any
                          + (size_t)(wave * (NTPW * 16) + l15) * D_DIM + quad * 8;
        for (int step = 0; step < 32; ++step) {
            const int off = step * 32;
            bf16x8 af[MT];
            #pragma unroll
            for (int m = 0; m < MT; ++m) {
                float4 a0 = *reinterpret_cast<const float4*>(xb + m * 16 * D_DIM + off);
                float4 a1 = *reinterpret_cast<const float4*>(xb + m * 16 * D_DIM + off + 4);
                af[m] = cvt8(a0, a1);
            }
            #pragma unroll
            for (int n = 0; n < NTPW; ++n) {
                float4 b0 = *reinterpret_cast<const float4*>(bf32 + n * 16 * D_DIM + off);
                float4 b1v = *reinterpret_cast<const float4*>(bf32 + n * 16 * D_DIM + off + 4);
                const bf16x8 bfr = cvt8(b0, b1v);
                #pragma unroll
                for (int m = 0; m < MT; ++m)
                    acc[m][n] = __builtin_amdgcn_mfma_f32_16x16x32_bf16(
                        af[m], bfr, acc[m][n], 0, 0, 0);
            }
        }
    }

    // ---- epilogue ----
    // C/D layout: col = l15 (within tile), row = quad*4 + reg   [m89/m91]
    const float fcw0 = fcw[l15 & 3];        // fc_w[0][k], k = col&3
    const float fcw1 = fcw[4 + (l15 & 3)];  // fc_w[1][k]

    float p0[MT][4], p1[MT][4];
    #pragma unroll
    for (int m = 0; m < MT; ++m)
        #pragma unroll
        for (int r = 0; r < 4; ++r) { p0[m][r] = 0.f; p1[m][r] = 0.f; }

    #pragma unroll
    for (int n = 0; n < NTPW; ++n) {
        const int col = (wave * NTPW + n) * 16 + l15;   // global n index
        const float bias = b1[col];
        const float tw   = fw[col >> 2];                // final_weight[t]
        #pragma unroll
        for (int m = 0; m < MT; ++m) {
            #pragma unroll
            for (int r = 0; r < 4; ++r) {
                float split = acc[m][n][r] + bias;
                float s = split;                         // sum over k: lanes ^1, ^2
                s += __shfl_xor(s, 1);
                s += __shfl_xor(s, 2);
                float leaf = 1.0f / (1.0f + __expf(-split));
                float val  = tw * leaf * s;
                p0[m][r] += val * fcw0;
                p1[m][r] += val * fcw1;
            }
        }
    }

    // butterfly over the 16 cols (lane bits 0-3), stash per-wave partials
    #pragma unroll
    for (int m = 0; m < MT; ++m) {
        #pragma unroll
        for (int r = 0; r < 4; ++r) {
            float a0s = p0[m][r], a1s = p1[m][r];
            #pragma unroll
            for (int mask = 1; mask < 16; mask <<= 1) {
                a0s += __shfl_xor(a0s, mask);
                a1s += __shfl_xor(a1s, mask);
            }
            const int row = m * 16 + quad * 4 + r;      // 0..63 within block
            if (l15 == 0) Pbuf[(row * 5 + wave) * 2 + 0] = a0s;
            if (l15 == 1) Pbuf[(row * 5 + wave) * 2 + 1] = a1s;
        }
    }
    __syncthreads();

    if (tid < 2 * 64) {
        const int r = tid >> 1, j = tid & 1;
        float s = fcb[j];
        #pragma unroll
        for (int w = 0; w < 5; ++w)
            s += Pbuf[(r * 5 + w) * 2 + j];
        out[(row0 + r) * 2 + j] = s;
    }
}

extern "C" void kernel_launch(void* const* d_in, const int* in_sizes, int n_in,
                              void* d_out, int out_size, void* d_ws, size_t ws_size,
                              hipStream_t stream) {
    const float* x   = (const float*)d_in[0];
    const float* W1  = (const float*)d_in[1];
    const float* b1  = (const float*)d_in[2];
    const float* fw  = (const float*)d_in[3];
    const float* fcw = (const float*)d_in[4];
    const float* fcb = (const float*)d_in[5];
    float* out = (float*)d_out;

    const size_t w1_elems = (size_t)N_COLS * D_DIM;   // 409600
    if (ws_size >= w1_elems * sizeof(unsigned short)) {
        unsigned short* w1b = (unsigned short*)d_ws;
        cvt_w1_kernel<<<(int)(w1_elems / 1024), 256, 0, stream>>>(W1, w1b);
        xgb_fused_v2<true><<<B_ROWS / 64, THREADS, 0, stream>>>(
            x, (const void*)w1b, b1, fw, fcw, fcb, out);
    } else {
        xgb_fused_v2<false><<<B_ROWS / 64, THREADS, 0, stream>>>(
            x, (const void*)W1, b1, fw, fcw, fcb, out);
    }
}

// Round 3
// 305.128 us; speedup vs baseline: 1.0074x; 1.0074x over previous
//
#include <hip/hip_runtime.h>
#include <hip/hip_bf16.h>

// DifferentiableXGB: logits = epilogue(x @ W1^T + b1)
//   split[b,n] = sum_d x[b,d]*W1[n,d] + b1[n]          (n = t*4+k, N=400)
//   S[b,t] = sum_k split[b,t,k]
//   logits[b,j] = sum_t fw[t]*S[b,t]*sum_k sigmoid(split[b,t,k])*fc_w[j,k] + fc_b[j]
//
// V3: pre-convert x AND W1 to bf16 in d_ws (BW-bound cvt kernels), then a
// pure bf16 direct-to-register MFMA GEMM with a manual even/odd double
// buffer (no copies, no steady-state branches) so the software pipeline
// actually materializes in registers. R2 post-mortem: VGPR=124 proved the
// compiler sank the prefetch; this structure forces it.

typedef __bf16 bf16x8 __attribute__((ext_vector_type(8)));
typedef float f32x4 __attribute__((ext_vector_type(4)));

#define B_ROWS 32768
#define D_DIM  1024
#define N_COLS 400      // T*K = 100*4
#define THREADS 320     // 5 waves; wave w owns N-tiles [w*5, w*5+5)
#define NTPW 5
#define MT   4          // 64 rows/block -> 512 blocks

__device__ __forceinline__ unsigned short f2bf(float f) {
    unsigned int u = __float_as_uint(f);
    u += 0x7FFFu + ((u >> 16) & 1u);   // RTNE
    return (unsigned short)(u >> 16);
}

__device__ __forceinline__ unsigned int pk2(float a, float b) {
    return (unsigned int)f2bf(a) | ((unsigned int)f2bf(b) << 16);
}

__device__ __forceinline__ bf16x8 cvt8(float4 a, float4 b) {
    uint4 u;
    u.x = pk2(a.x, a.y); u.y = pk2(a.z, a.w);
    u.z = pk2(b.x, b.y); u.w = pk2(b.z, b.w);
    return __builtin_bit_cast(bf16x8, u);
}

// 8 elems/thread fp32 -> bf16
__global__ void cvt_f32_bf16_kernel(const float* __restrict__ in,
                                    unsigned short* __restrict__ out) {
    size_t i = ((size_t)blockIdx.x * 256 + threadIdx.x) * 8;
    float4 v0 = *reinterpret_cast<const float4*>(in + i);
    float4 v1 = *reinterpret_cast<const float4*>(in + i + 4);
    uint4 u;
    u.x = pk2(v0.x, v0.y); u.y = pk2(v0.z, v0.w);
    u.z = pk2(v1.x, v1.y); u.w = pk2(v1.z, v1.w);
    *reinterpret_cast<uint4*>(out + i) = u;
}

// MODE 0: A bf16 (ws), B bf16 (ws)  — fast path, dbuf
// MODE 1: A fp32 (in), B bf16 (ws)  — dbuf + in-reg cvt
// MODE 2: A fp32, B fp32            — emergency fallback, plain loop
template <int MODE>
__global__ __launch_bounds__(THREADS, 2) void xgb_v3(
    const void* __restrict__ a_any,
    const void* __restrict__ b_any,
    const float* __restrict__ b1,
    const float* __restrict__ fw,
    const float* __restrict__ fcw,      // [2,4]
    const float* __restrict__ fcb,      // [2]
    float* __restrict__ out)            // [B,2]
{
    __shared__ float Pbuf[64 * 5 * 2];

    const int tid  = threadIdx.x;
    const int wave = tid >> 6;
    const int lane = tid & 63;
    const int quad = lane >> 4;
    const int l15  = lane & 15;
    const int row0 = blockIdx.x * 64;

    f32x4 acc[MT][NTPW] = {};

    // A-frag: A[m=l15][k=quad*8+j]; B-frag: B[k=quad*8+j][n=l15] (W1 row n)
    const unsigned short* ab = nullptr;
    const float*          af = nullptr;
    if (MODE == 0)
        ab = (const unsigned short*)a_any + (size_t)(row0 + l15) * D_DIM + quad * 8;
    else
        af = (const float*)a_any + (size_t)(row0 + l15) * D_DIM + quad * 8;

    if (MODE <= 1) {
        const unsigned short* bb = (const unsigned short*)b_any
                                 + (size_t)(wave * (NTPW * 16) + l15) * D_DIM + quad * 8;

        uint4  A0[MT], A1[MT];          // MODE 0 A buffers
        float4 F0[MT][2], F1[MT][2];    // MODE 1 A buffers
        uint4  B0[NTPW], B1[NTPW];

        auto load = [&](int off, uint4* A, float4 (*F)[2], uint4* B) {
            #pragma unroll
            for (int m = 0; m < MT; ++m) {
                if (MODE == 0) {
                    A[m] = *reinterpret_cast<const uint4*>(ab + (size_t)m * 16 * D_DIM + off);
                } else {
                    F[m][0] = *reinterpret_cast<const float4*>(af + (size_t)m * 16 * D_DIM + off);
                    F[m][1] = *reinterpret_cast<const float4*>(af + (size_t)m * 16 * D_DIM + off + 4);
                }
            }
            #pragma unroll
            for (int n = 0; n < NTPW; ++n)
                B[n] = *reinterpret_cast<const uint4*>(bb + (size_t)n * 16 * D_DIM + off);
        };
        auto compute = [&](uint4* A, float4 (*F)[2], uint4* B) {
            bf16x8 afr[MT];
            #pragma unroll
            for (int m = 0; m < MT; ++m)
                afr[m] = (MODE == 0) ? __builtin_bit_cast(bf16x8, A[m])
                                     : cvt8(F[m][0], F[m][1]);
            #pragma unroll
            for (int n = 0; n < NTPW; ++n) {
                const bf16x8 bfr = __builtin_bit_cast(bf16x8, B[n]);
                #pragma unroll
                for (int m = 0; m < MT; ++m)
                    acc[m][n] = __builtin_amdgcn_mfma_f32_16x16x32_bf16(
                        afr[m], bfr, acc[m][n], 0, 0, 0);
            }
        };

        load(0, A0, F0, B0);
        int kc = 0;
        #pragma unroll 1
        for (int it = 0; it < 15; ++it) {   // pairs of K-steps: 30 steps
            load(kc + 32, A1, F1, B1);
            compute(A0, F0, B0);
            load(kc + 64, A0, F0, B0);
            compute(A1, F1, B1);
            kc += 64;
        }
        load(992, A1, F1, B1);              // steps 31, 32
        compute(A0, F0, B0);
        compute(A1, F1, B1);
    } else {
        // both fp32, no ws: plain loop (correctness insurance only)
        const float* bf32 = (const float*)b_any
                          + (size_t)(wave * (NTPW * 16) + l15) * D_DIM + quad * 8;
        for (int step = 0; step < 32; ++step) {
            const int off = step * 32;
            bf16x8 afr[MT];
            #pragma unroll
            for (int m = 0; m < MT; ++m) {
                float4 a0 = *reinterpret_cast<const float4*>(af + (size_t)m * 16 * D_DIM + off);
                float4 a1 = *reinterpret_cast<const float4*>(af + (size_t)m * 16 * D_DIM + off + 4);
                afr[m] = cvt8(a0, a1);
            }
            #pragma unroll
            for (int n = 0; n < NTPW; ++n) {
                float4 b0v = *reinterpret_cast<const float4*>(bf32 + (size_t)n * 16 * D_DIM + off);
                float4 b1v = *reinterpret_cast<const float4*>(bf32 + (size_t)n * 16 * D_DIM + off + 4);
                const bf16x8 bfr = cvt8(b0v, b1v);
                #pragma unroll
                for (int m = 0; m < MT; ++m)
                    acc[m][n] = __builtin_amdgcn_mfma_f32_16x16x32_bf16(
                        afr[m], bfr, acc[m][n], 0, 0, 0);
            }
        }
    }

    // ---- epilogue ----
    // C/D layout: col = l15 (within tile), row = quad*4 + reg   [m89/m91]
    const float fcw0 = fcw[l15 & 3];        // fc_w[0][k], k = col&3
    const float fcw1 = fcw[4 + (l15 & 3)];  // fc_w[1][k]

    float p0[MT][4], p1[MT][4];
    #pragma unroll
    for (int m = 0; m < MT; ++m)
        #pragma unroll
        for (int r = 0; r < 4; ++r) { p0[m][r] = 0.f; p1[m][r] = 0.f; }

    #pragma unroll
    for (int n = 0; n < NTPW; ++n) {
        const int col = (wave * NTPW + n) * 16 + l15;   // global n index
        const float bias = b1[col];
        const float tw   = fw[col >> 2];                // final_weight[t]
        #pragma unroll
        for (int m = 0; m < MT; ++m) {
            #pragma unroll
            for (int r = 0; r < 4; ++r) {
                float split = acc[m][n][r] + bias;
                float s = split;                         // sum over k: lanes ^1, ^2
                s += __shfl_xor(s, 1);
                s += __shfl_xor(s, 2);
                float leaf = 1.0f / (1.0f + __expf(-split));
                float val  = tw * leaf * s;
                p0[m][r] += val * fcw0;
                p1[m][r] += val * fcw1;
            }
        }
    }

    #pragma unroll
    for (int m = 0; m < MT; ++m) {
        #pragma unroll
        for (int r = 0; r < 4; ++r) {
            float a0s = p0[m][r], a1s = p1[m][r];
            #pragma unroll
            for (int mask = 1; mask < 16; mask <<= 1) {
                a0s += __shfl_xor(a0s, mask);
                a1s += __shfl_xor(a1s, mask);
            }
            const int row = m * 16 + quad * 4 + r;      // 0..63 within block
            if (l15 == 0) Pbuf[(row * 5 + wave) * 2 + 0] = a0s;
            if (l15 == 1) Pbuf[(row * 5 + wave) * 2 + 1] = a1s;
        }
    }
    __syncthreads();

    if (tid < 2 * 64) {
        const int r = tid >> 1, j = tid & 1;
        float s = fcb[j];
        #pragma unroll
        for (int w = 0; w < 5; ++w)
            s += Pbuf[(r * 5 + w) * 2 + j];
        out[(row0 + r) * 2 + j] = s;
    }
}

extern "C" void kernel_launch(void* const* d_in, const int* in_sizes, int n_in,
                              void* d_out, int out_size, void* d_ws, size_t ws_size,
                              hipStream_t stream) {
    const float* x   = (const float*)d_in[0];
    const float* W1  = (const float*)d_in[1];
    const float* b1  = (const float*)d_in[2];
    const float* fw  = (const float*)d_in[3];
    const float* fcw = (const float*)d_in[4];
    const float* fcb = (const float*)d_in[5];
    float* out = (float*)d_out;

    const size_t x_elems  = (size_t)B_ROWS * D_DIM;   // 33,554,432
    const size_t w1_elems = (size_t)N_COLS * D_DIM;   // 409,600
    const size_t need_full = (x_elems + w1_elems) * sizeof(unsigned short);
    const size_t need_w1   = w1_elems * sizeof(unsigned short);

    if (ws_size >= need_full) {
        unsigned short* xb  = (unsigned short*)d_ws;
        unsigned short* w1b = xb + x_elems;
        cvt_f32_bf16_kernel<<<(int)(x_elems / 2048), 256, 0, stream>>>(x, xb);
        cvt_f32_bf16_kernel<<<(int)(w1_elems / 2048), 256, 0, stream>>>(W1, w1b);
        xgb_v3<0><<<B_ROWS / 64, THREADS, 0, stream>>>(
            (const void*)xb, (const void*)w1b, b1, fw, fcw, fcb, out);
    } else if (ws_size >= need_w1) {
        unsigned short* w1b = (unsigned short*)d_ws;
        cvt_f32_bf16_kernel<<<(int)(w1_elems / 2048), 256, 0, stream>>>(W1, w1b);
        xgb_v3<1><<<B_ROWS / 64, THREADS, 0, stream>>>(
            (const void*)x, (const void*)w1b, b1, fw, fcw, fcb, out);
    } else {
        xgb_v3<2><<<B_ROWS / 64, THREADS, 0, stream>>>(
            (const void*)x, (const void*)W1, b1, fw, fcw, fcb, out);
    }
}